// Round 16
// baseline (86.538 us; speedup 1.0000x reference)
//
#include <hip/hip_runtime.h>

#define HW_  4096
#define DQK  131072     // 32*4096 per batch (q or k)
#define DV   1048576    // 256*4096 per batch

using bf16x8 = __attribute__((ext_vector_type(8))) __bf16;
using f32x4  = __attribute__((ext_vector_type(4))) float;
using u16x8  = __attribute__((ext_vector_type(8))) unsigned short;

static __device__ __forceinline__ unsigned short f2bf(float f) {
    union { float f; unsigned u; } v; v.f = f;
    unsigned r = v.u + 0x7FFFu + ((v.u >> 16) & 1u);
    return (unsigned short)(r >> 16);
}
static __device__ __forceinline__ float bf2f(unsigned short h) {
    union { unsigned u; float f; } v; v.u = ((unsigned)h) << 16;
    return v.f;
}

// ---------------- pack weights into MFMA A-fragment layout (r11-validated):
// addr(m,c) = (m>>4)*4096 + (c>>3)*128 + (m&15)*8 + (c&7)
__global__ __launch_bounds__(256) void k_pack(const float* wq, const float* wk, const float* wv,
                                              unsigned short* WhF, unsigned short* WlF, unsigned short* WvF) {
    int idx = blockIdx.x * 256 + threadIdx.x;   // 81920 total
    if (idx < 16384) {
        int i = idx;
        int mt = i >> 12, cg = (i >> 7) & 31, ml = (i >> 3) & 15, cl = i & 7;
        int m = mt * 16 + ml, c = cg * 8 + cl;
        float f = (m < 32) ? wq[m * 256 + c] : wk[(m - 32) * 256 + c];
        unsigned short hi = f2bf(f);
        WhF[i] = hi;
        WlF[i] = f2bf(f - bf2f(hi));
    } else {
        int i = idx - 16384;
        int mt = i >> 12, kt = (i >> 7) & 31, lr = (i >> 3) & 15, j = i & 7;
        int m = mt * 16 + lr, c = kt * 8 + j;
        WvF[i] = f2bf(wv[m * 256 + c]);
    }
}

// ---------------- qk GEMM, split-bf16, LDS-transposed B staging.
// Staging: coalesced f32x4 reads (32c x 64n chunk, 4x256B segments/instr), in-reg hi/lo split,
// bank-swizzled LDS store; B-frags via ds_read_b128 (2-way = free). Next chunk reg-prefetched.
// QF/KF stored FLAT: b*DQK + nblk*2048 + slot*256 + lane*4 + i.
__global__ __launch_bounds__(256, 4) void k_gemm_qk(const unsigned short* __restrict__ WhF,
                                                    const unsigned short* __restrict__ WlF,
                                                    const float* __restrict__ x,
                                                    const float* __restrict__ bq, const float* __restrict__ bk,
                                                    float* __restrict__ QF, float* __restrict__ KF) {
    __shared__ __align__(16) __bf16 Bh[64][40], Bl[64][40];   // 40-elem rows: b128-aligned, swizzle-friendly
    int b  = blockIdx.y;
    int n0 = blockIdx.x * 64;
    int t = threadIdx.x;
    int lane = t & 63, wid = t >> 6;
    int wm = wid & 1, wn = wid >> 1;
    int lr = lane & 15, kg = lane >> 4;

    int nl = t & 15, cr = t >> 4;              // staging: col n0+nl*4, rows {cr, cr+16} per 32-c chunk
    const float* xs = x + (size_t)b * DV + n0 + nl * 4;

    const unsigned short* Ah0 = WhF + (size_t)(wm * 2) * 4096 + lane * 8;
    const unsigned short* Al0 = WlF + (size_t)(wm * 2) * 4096 + lane * 8;

    f32x4 acc[2][2];
    #pragma unroll
    for (int mi = 0; mi < 2; mi++)
        #pragma unroll
        for (int ni = 0; ni < 2; ni++) acc[mi][ni] = (f32x4){0.f, 0.f, 0.f, 0.f};

    f32x4 v0 = *(const f32x4*)(xs + (size_t)cr * HW_);
    f32x4 v1 = *(const f32x4*)(xs + (size_t)(16 + cr) * HW_);

    int oct0 = cr >> 3, oct1 = (16 + cr) >> 3, cb = cr & 7, nl3 = nl & 3;

    #pragma unroll
    for (int kk = 0; kk < 8; kk++) {
        // write current chunk to LDS (hi/lo split), swizzled
        #pragma unroll
        for (int e = 0; e < 4; e++) {
            int n  = nl * 4 + e;
            int s0 = (oct0 ^ e ^ nl3) * 8 + cb;
            int s1 = (oct1 ^ e ^ nl3) * 8 + cb;
            float f0 = v0[e]; __bf16 h0 = (__bf16)f0;
            Bh[n][s0] = h0; Bl[n][s0] = (__bf16)(f0 - (float)h0);
            float f1 = v1[e]; __bf16 h1 = (__bf16)f1;
            Bh[n][s1] = h1; Bl[n][s1] = (__bf16)(f1 - (float)h1);
        }
        __syncthreads();
        if (kk < 7) {                           // prefetch next chunk (overlaps LDS reads + MFMA)
            v0 = *(const f32x4*)(xs + (size_t)((kk + 1) * 32 + cr) * HW_);
            v1 = *(const f32x4*)(xs + (size_t)((kk + 1) * 32 + 16 + cr) * HW_);
        }
        bf16x8 ah[2], al[2];
        #pragma unroll
        for (int mi = 0; mi < 2; mi++) {
            ah[mi] = *(const bf16x8*)(Ah0 + (size_t)mi * 4096 + kk * 512);
            al[mi] = *(const bf16x8*)(Al0 + (size_t)mi * 4096 + kk * 512);
        }
        bf16x8 bh[2], bl[2];
        #pragma unroll
        for (int ni = 0; ni < 2; ni++) {
            int n  = wn * 32 + ni * 16 + lr;
            int co = (kg ^ (n & 3) ^ ((n >> 2) & 3)) * 8;
            bh[ni] = *(const bf16x8*)&Bh[n][co];
            bl[ni] = *(const bf16x8*)&Bl[n][co];
        }
        #pragma unroll
        for (int mi = 0; mi < 2; mi++)
            #pragma unroll
            for (int ni = 0; ni < 2; ni++) {
                acc[mi][ni] = __builtin_amdgcn_mfma_f32_16x16x32_bf16(ah[mi], bh[ni], acc[mi][ni], 0, 0, 0);
                acc[mi][ni] = __builtin_amdgcn_mfma_f32_16x16x32_bf16(ah[mi], bl[ni], acc[mi][ni], 0, 0, 0);
                acc[mi][ni] = __builtin_amdgcn_mfma_f32_16x16x32_bf16(al[mi], bh[ni], acc[mi][ni], 0, 0, 0);
            }
        __syncthreads();
    }

    float* dst = (wm == 0) ? QF : KF;
    const float* bias = (wm == 0) ? bq : bk;
    size_t base = (size_t)b * DQK + (size_t)blockIdx.x * 2048;
    #pragma unroll
    for (int mi = 0; mi < 2; mi++) {
        f32x4 bvv = *(const f32x4*)(bias + mi * 16 + kg * 4);
        #pragma unroll
        for (int ni = 0; ni < 2; ni++) {
            int slot = (wn * 2 + ni) * 2 + mi;
            f32x4 v = acc[mi][ni] + bvv;
            *(f32x4*)(dst + base + slot * 256 + lane * 4) = v;
        }
    }
}

// ---------------- scores: 256 blocks, each owns a flat 512-elem slice for ALL 16 batches (r11-validated).
__global__ __launch_bounds__(256) void k_scores2(const float* __restrict__ QF, const float* __restrict__ KF,
                                                 float* __restrict__ Sp) {
    __shared__ float Ql[16][520], Kl[16][520];
    int s = blockIdx.x;
    size_t off = (size_t)s * 512;
    int t = threadIdx.x;
    for (int b = 0; b < 16; b++) {
        const float* qs = QF + (size_t)b * DQK + off;
        const float* ks = KF + (size_t)b * DQK + off;
        Ql[b][t]       = qs[t];
        Ql[b][t + 256] = qs[t + 256];
        Kl[b][t]       = ks[t];
        Kl[b][t + 256] = ks[t + 256];
    }
    __syncthreads();
    int p = t >> 1, h = t & 1;
    int b = p >> 3, j = p & 7;
    int hb = b >> 2, wb = b & 3;
    int bp = (j < 4) ? (j * 4 + wb) : (hb * 4 + (j - 4));
    const f32x4* q4 = (const f32x4*)&Ql[b][h * 256];
    const f32x4* k4 = (const f32x4*)&Kl[bp][h * 256];
    f32x4 a4 = (f32x4){0.f, 0.f, 0.f, 0.f};
    for (int i = 0; i < 64; i++) a4 += q4[i] * k4[i];
    float sres = a4[0] + a4[1] + a4[2] + a4[3];
    sres += __shfl_xor(sres, 1);
    if (h == 0) Sp[(size_t)p * 256 + s] = sres;
}

// ---------------- reduce slices + softmax + fold gamma -> M [0..255] + rowsum [256..271]
__global__ void k_softmax2(const float* __restrict__ Sp, const float* __restrict__ gamma,
                           float* __restrict__ Mm) {
    __shared__ float SS[128];
    int t = threadIdx.x;
    const f32x4* s4 = (const f32x4*)(Sp + (size_t)t * 256);
    f32x4 a = (f32x4){0.f, 0.f, 0.f, 0.f};
    for (int i = 0; i < 64; i++) a += s4[i];
    SS[t] = a[0] + a[1] + a[2] + a[3];
    __syncthreads();
    if (t < 16) {
        int b = t, h = b >> 2, w = b & 3;
        float e[8];
        for (int j = 0; j < 8; j++) e[j] = SS[b * 8 + j];
        e[h] = -INFINITY;
        float mx = e[0];
        for (int j = 1; j < 8; j++) mx = fmaxf(mx, e[j]);
        float aa[8], sum = 0.f;
        for (int j = 0; j < 8; j++) { aa[j] = expf(e[j] - mx); sum += aa[j]; }
        float inv = 1.0f / sum;
        float g = gamma[0];
        float row[16];
        for (int c = 0; c < 16; c++) row[c] = 0.f;
        for (int gg = 0; gg < 4; gg++) if (gg != h) row[gg * 4 + w] += aa[gg] * inv;
        for (int gg = 0; gg < 4; gg++) row[h * 4 + gg] += aa[4 + gg] * inv;
        for (int c = 0; c < 16; c++) Mm[b * 16 + c] = row[c] * g;
        Mm[256 + b] = g;
    }
}

// ---------------- mix + transpose + convert -> pre-fragmented Xm (r11-validated).
// Xm addr(b,p,c) = b*DV + (p>>4)*4096 + (c>>3)*128 + (p&15)*8 + (c&7).
__global__ __launch_bounds__(256) void k_mix(const float* __restrict__ Mm, const float* __restrict__ x,
                                             unsigned short* __restrict__ Xm) {
    __shared__ float Ms[256];
    __shared__ __align__(16) unsigned short T[16][32][40];
    int t = threadIdx.x;
    int p0 = blockIdx.x * 32, c0 = blockIdx.y * 32;
    Ms[t] = Mm[t];

    int c_l = t >> 3, p4 = t & 7;
    f32x4 in4[16];
    for (int bp = 0; bp < 16; bp++)
        in4[bp] = *(const f32x4*)(x + (size_t)bp * DV + (size_t)(c0 + c_l) * HW_ + p0 + p4 * 4);
    __syncthreads();
    for (int b = 0; b < 16; b++) {
        int h = b >> 2, w = b & 3;
        f32x4 acc = (f32x4){0.f, 0.f, 0.f, 0.f};
        #pragma unroll
        for (int g = 0; g < 4; g++) {
            if (g != h) acc += Ms[b * 16 + g * 4 + w] * in4[g * 4 + w];
            acc += Ms[b * 16 + h * 4 + g] * in4[h * 4 + g];
        }
        for (int e = 0; e < 4; e++) T[b][p4 * 4 + e][c_l] = f2bf(acc[e]);
    }
    __syncthreads();
    int p_l = t & 31, co = (t >> 5) & 3, bh = t >> 7;
    int p = p0 + p_l;
    int c = c0 + co * 8;
    size_t dst = (size_t)(p >> 4) * 4096 + (size_t)(c >> 3) * 128 + (p & 15) * 8;
    #pragma unroll
    for (int bi = 0; bi < 8; bi++) {
        int b = bh * 8 + bi;
        u16x8 v = *(const u16x8*)&T[b][p_l][co * 8];
        *(u16x8*)(Xm + (size_t)b * DV + dst) = v;
    }
}

// ---------------- v GEMM + bias + residual: NO-LDS k-loop; LDS-staged coalesced epilogue
// with nontemporal out stores (r11-validated).
__global__ __launch_bounds__(512) void k_gemm_v_res(const unsigned short* __restrict__ WvF,
                                                    const unsigned short* __restrict__ XmF,
                                                    const float* __restrict__ bv,
                                                    const float* __restrict__ MmRs,
                                                    const float* __restrict__ x,
                                                    float* __restrict__ out) {
    __shared__ __align__(16) float LD[256][68];
    int b  = blockIdx.y;
    int n0 = blockIdx.x * 64;
    int t = threadIdx.x;
    int lane = t & 63, wid = t >> 6;
    int wm = wid >> 1, wn = wid & 1;
    int lr = lane & 15, kg = lane >> 4;

    const unsigned short* Bb = XmF + (size_t)b * DV + (size_t)(blockIdx.x * 4 + wn * 2) * 4096 + lane * 8;
    const unsigned short* Ab = WvF + (size_t)(wm * 4) * 4096 + lane * 8;

    bf16x8 bfr[8][2];
    #pragma unroll
    for (int kk = 0; kk < 8; kk++)
        #pragma unroll
        for (int ni = 0; ni < 2; ni++)
            bfr[kk][ni] = *(const bf16x8*)(Bb + (size_t)ni * 4096 + kk * 512);

    f32x4 acc[4][2];
    #pragma unroll
    for (int mi = 0; mi < 4; mi++)
        for (int ni = 0; ni < 2; ni++) acc[mi][ni] = (f32x4){0.f, 0.f, 0.f, 0.f};

    bf16x8 a[4], an[4];
    #pragma unroll
    for (int mi = 0; mi < 4; mi++) a[mi] = *(const bf16x8*)(Ab + (size_t)mi * 4096);
    #pragma unroll
    for (int kk = 0; kk < 8; kk++) {
        if (kk < 7) {
            #pragma unroll
            for (int mi = 0; mi < 4; mi++)
                an[mi] = *(const bf16x8*)(Ab + (size_t)mi * 4096 + (kk + 1) * 512);
        }
        #pragma unroll
        for (int mi = 0; mi < 4; mi++)
            #pragma unroll
            for (int ni = 0; ni < 2; ni++)
                acc[mi][ni] = __builtin_amdgcn_mfma_f32_16x16x32_bf16(a[mi], bfr[kk][ni], acc[mi][ni], 0, 0, 0);
        #pragma unroll
        for (int mi = 0; mi < 4; mi++) a[mi] = an[mi];
    }

    float rs = MmRs[256 + b];
    #pragma unroll
    for (int mi = 0; mi < 4; mi++) {
        int mrow0 = wm * 64 + mi * 16 + kg * 4;
        f32x4 bvv = *(const f32x4*)(bv + mrow0);
        #pragma unroll
        for (int ni = 0; ni < 2; ni++) {
            f32x4 mo = acc[mi][ni] + rs * bvv;
            int ncol = wn * 32 + ni * 16 + lr;
            #pragma unroll
            for (int i = 0; i < 4; i++) LD[mrow0 + i][ncol] = mo[i];
        }
    }
    __syncthreads();
    #pragma unroll
    for (int ps = 0; ps < 8; ps++) {
        int row = wid * 32 + ps * 4 + (lane >> 4);
        int nc  = (lane & 15) * 4;
        f32x4 o = *(const f32x4*)&LD[row][nc];
        size_t g = (size_t)b * DV + (size_t)row * HW_ + n0 + nc;
        f32x4 rr = *(const f32x4*)(x + g);
        __builtin_nontemporal_store(o + rr, (f32x4*)(out + g));
    }
}

extern "C" void kernel_launch(void* const* d_in, const int* in_sizes, int n_in,
                              void* d_out, int out_size, void* d_ws, size_t ws_size,
                              hipStream_t stream) {
    (void)in_sizes; (void)n_in; (void)out_size; (void)ws_size;
    const float* x     = (const float*)d_in[0];
    const float* wq    = (const float*)d_in[1];
    const float* bq    = (const float*)d_in[2];
    const float* wk    = (const float*)d_in[3];
    const float* bk    = (const float*)d_in[4];
    const float* wv    = (const float*)d_in[5];
    const float* bv    = (const float*)d_in[6];
    const float* gamma = (const float*)d_in[7];

    char* ws = (char*)d_ws;
    // ws layout: WhF 32768 | WlF 32768 | WvF 131072 | QF 8388608 | KF 8388608 | Xm 33554432
    // Aliases (lifetime-disjoint): Mm@0 (WhF dead after qk); Sp@Xm-start (dead before mix writes).
    unsigned short* WhF = (unsigned short*)(ws + 0);
    unsigned short* WlF = (unsigned short*)(ws + 32768);
    unsigned short* WvF = (unsigned short*)(ws + 65536);
    float*          QF  = (float*)(ws + 196608);
    float*          KF  = (float*)(ws + 8585216);
    unsigned short* Xm  = (unsigned short*)(ws + 16973824);  // +33554432 = 50528256 total
    float*          Sp  = (float*)(ws + 16973824);           // aliases Xm (dead before mix)
    float*          Mm  = (float*)(ws + 0);                  // aliases WhF (dead by then)
    float*          vo  = (float*)d_out;

    k_pack       <<<320, 256, 0, stream>>>(wq, wk, wv, WhF, WlF, WvF);
    k_gemm_qk    <<<dim3(64, 16), 256, 0, stream>>>(WhF, WlF, x, bq, bk, QF, KF);
    k_scores2    <<<256, 256, 0, stream>>>(QF, KF, Sp);
    k_softmax2   <<<1, 128, 0, stream>>>(Sp, gamma, Mm);
    k_mix        <<<dim3(128, 8), 256, 0, stream>>>(Mm, x, Xm);
    k_gemm_v_res <<<dim3(64, 16), 512, 0, stream>>>(WvF, Xm, bv, Mm, x, vo);
}